// Round 1
// baseline (19.216 us; speedup 1.0000x reference)
//
#include <hip/hip_runtime.h>
#include <hip/hip_bf16.h>

// CoFiSet scoring: out[0][b] = mean_s(u_b . v_{p_bs} + bi_{p_bs}),
//                  out[1][b] = u_b . v_{n_b} + bi_{n_b}
// U: [1e6,64] f32, V: [1e5,64] f32, bi: [1e5] f32
// user_id: [B] i32, pos_item_id: [B,20] i32, neg_item_id: [B] i32
// One wave64 per batch row; lane == embedding dim.

#define DIM 64
#define NPOS 20

__global__ __launch_bounds__(256) void cofiset_kernel(
    const float* __restrict__ U,
    const float* __restrict__ V,
    const float* __restrict__ bi,
    const int*   __restrict__ user_id,
    const int*   __restrict__ pos_item_id,
    const int*   __restrict__ neg_item_id,
    float* __restrict__ out,
    int B)
{
    const int row  = (int)((blockIdx.x * blockDim.x + threadIdx.x) >> 6);
    const int lane = (int)(threadIdx.x & 63);
    if (row >= B) return;

    // --- gather user embedding: lane i holds u[i] (coalesced 256B row) ---
    const int uid = user_id[row];
    const float u = U[(size_t)uid * DIM + lane];

    // --- lane l < NPOS holds pos index l and its bias ---
    int   pidx  = 0;
    float pbias = 0.0f;
    if (lane < NPOS) {
        pidx  = pos_item_id[row * NPOS + lane];
        pbias = bi[pidx];
    }

    // --- accumulate sum_s u[lane]*V[p_s][lane]; biases folded into partials ---
    float accp = pbias;
    #pragma unroll
    for (int s = 0; s < NPOS; ++s) {
        const int idx = __shfl(pidx, s);              // uniform -> readlane/SGPR base
        const float v = V[(size_t)idx * DIM + lane];
        accp = fmaf(u, v, accp);
    }

    // --- negative item ---
    const int nidx = neg_item_id[row];
    const float vn = V[(size_t)nidx * DIM + lane];
    float accn = u * vn;

    // --- one butterfly reduction over 64 lanes for both accumulators ---
    #pragma unroll
    for (int off = 32; off >= 1; off >>= 1) {
        accp += __shfl_xor(accp, off);
        accn += __shfl_xor(accn, off);
    }

    if (lane == 0) {
        out[row]     = accp * (1.0f / (float)NPOS);
        out[B + row] = accn + bi[nidx];
    }
}

extern "C" void kernel_launch(void* const* d_in, const int* in_sizes, int n_in,
                              void* d_out, int out_size, void* d_ws, size_t ws_size,
                              hipStream_t stream) {
    const float* U   = (const float*)d_in[0];
    const float* V   = (const float*)d_in[1];
    const float* bi  = (const float*)d_in[2];
    const int* user_id     = (const int*)d_in[3];
    const int* pos_item_id = (const int*)d_in[4];
    const int* neg_item_id = (const int*)d_in[5];
    float* out = (float*)d_out;

    const int B = in_sizes[3];                 // 16384
    const int rows_per_block = 256 / 64;       // 4 waves/block
    const int grid = (B + rows_per_block - 1) / rows_per_block;

    cofiset_kernel<<<grid, 256, 0, stream>>>(U, V, bi, user_id, pos_item_id,
                                             neg_item_id, out, B);
}

// Round 2
// 18.585 us; speedup vs baseline: 1.0339x; 1.0339x over previous
//
#include <hip/hip_runtime.h>
#include <hip/hip_bf16.h>

// CoFiSet scoring: out[0][b] = mean_s(u_b . v_{p_bs} + bi_{p_bs}),
//                  out[1][b] = u_b . v_{n_b} + bi_{n_b}
// U: [1e6,64] f32, V: [1e5,64] f32, bi: [1e5] f32
// Layout: 4 batch rows per wave64. lane = 16*r + q ; r = sub-row, q = dim/4.
// Each lane loads float4 -> every vmem instruction moves 1 KB (4 rows x 256 B),
// 4x the bytes-in-flight per outstanding request vs the 1-row/wave version.

#define DIM 64
#define NPOS 20

__global__ __launch_bounds__(256) void cofiset_kernel(
    const float* __restrict__ U,
    const float* __restrict__ V,
    const float* __restrict__ bi,
    const int*   __restrict__ user_id,
    const int*   __restrict__ pos_item_id,
    const int*   __restrict__ neg_item_id,
    float* __restrict__ out,
    int B)
{
    const int gwave = (int)((blockIdx.x * blockDim.x + threadIdx.x) >> 6);
    const int lane  = (int)(threadIdx.x & 63);
    const int r     = lane >> 4;        // sub-row within wave (0..3)
    const int q     = lane & 15;        // 16-byte chunk within row (0..15)
    const int row   = gwave * 4 + r;    // batch row
    if (row >= B) return;               // grid sized exactly; no divergence in practice

    // ---- issue all index loads up front ----
    const int uid  = user_id[row];
    const int nidx = neg_item_id[row];
    const int pidx  = pos_item_id[row * NPOS + q];                        // items 0..15
    const int pidx2 = (q < 4) ? pos_item_id[row * NPOS + 16 + q] : 0;     // items 16..19

    // ---- user embedding chunk (1 instr: 4 scattered 256B rows) ----
    const float4 u4 = *(const float4*)&U[(size_t)uid * DIM + q * 4];

    // ---- bias partials: this lane's items' biases; summed in the reduction ----
    float acc = bi[pidx] + ((q < 4) ? bi[pidx2] : 0.0f);
    const float nb = bi[nidx];

    // ---- negative item ----
    const float4 vn = *(const float4*)&V[(size_t)nidx * DIM + q * 4];
    float accn = u4.x * vn.x + u4.y * vn.y + u4.z * vn.z + u4.w * vn.w;

    // ---- 20 positive items: broadcast index within the 16-lane group ----
    const int grp = lane & 48;
    #pragma unroll
    for (int s = 0; s < NPOS; ++s) {
        const int idx = (s < 16) ? __shfl(pidx,  grp + s)
                                 : __shfl(pidx2, grp + (s - 16));
        const float4 v4 = *(const float4*)&V[(size_t)idx * DIM + q * 4];
        acc = fmaf(u4.x, v4.x, acc);
        acc = fmaf(u4.y, v4.y, acc);
        acc = fmaf(u4.z, v4.z, acc);
        acc = fmaf(u4.w, v4.w, acc);
    }

    // ---- reduce within each 16-lane group (sums dots + biases) ----
    #pragma unroll
    for (int off = 8; off >= 1; off >>= 1) {
        acc  += __shfl_xor(acc,  off);
        accn += __shfl_xor(accn, off);
    }

    if (q == 0) {
        out[row]     = acc * (1.0f / (float)NPOS);
        out[B + row] = accn + nb;
    }
}

extern "C" void kernel_launch(void* const* d_in, const int* in_sizes, int n_in,
                              void* d_out, int out_size, void* d_ws, size_t ws_size,
                              hipStream_t stream) {
    const float* U   = (const float*)d_in[0];
    const float* V   = (const float*)d_in[1];
    const float* bi  = (const float*)d_in[2];
    const int* user_id     = (const int*)d_in[3];
    const int* pos_item_id = (const int*)d_in[4];
    const int* neg_item_id = (const int*)d_in[5];
    float* out = (float*)d_out;

    const int B = in_sizes[3];                  // 16384
    const int rows_per_block = 4 * 4;           // 4 waves/block * 4 rows/wave
    const int grid = (B + rows_per_block - 1) / rows_per_block;   // 1024

    cofiset_kernel<<<grid, 256, 0, stream>>>(U, V, bi, user_id, pos_item_id,
                                             neg_item_id, out, B);
}